// Round 4
// baseline (480.423 us; speedup 1.0000x reference)
//
#include <hip/hip_runtime.h>

// GCN forward. Linearity reorder: layer1 aggregates x (D=128) BEFORE the GEMM.
//   ax = A·x                         (agg, D=128, no bias/relu)
//   a1 = relu(ax@W1 + b1)            (MFMA split-bf16 GEMM, fused epilogue)
//   h2 = a1@W2                       (MFMA split-bf16 GEMM)
//   a2 = relu(A·h2 + b2)             (agg, D=128, bias+relu)
//   out = meanpool(a2)@Wfc + bfc
// A = sym-norm adjacency with self-loops; CSR-by-dst built per call.
// GEMMs: f32 emulated as bf16 hi/lo split, 3 MFMAs (hi*hi + hi*lo + lo*hi);
// dropped lo*lo ~ 2^-18 rel -> ~1e-4 abs, threshold is 1.34e-3.

constexpr int IN_DIM  = 128;
constexpr int HID     = 256;
constexpr int HID2    = 128;
constexpr int OUT_DIM = 4;
constexpr int NGRAPH  = 64;
constexpr int PCH     = 64;   // nodes per pool block

typedef __attribute__((ext_vector_type(8))) short bf16x8;
typedef __attribute__((ext_vector_type(4))) float f32x4;

__device__ __forceinline__ short f2bf(float f) {
    union { float f; unsigned u; } v; v.f = f;
    unsigned r = v.u + 0x7fff + ((v.u >> 16) & 1);   // RNE
    return (short)(r >> 16);
}
__device__ __forceinline__ float bf2f(short s) {
    union { unsigned u; float f; } v; v.u = ((unsigned)(unsigned short)s) << 16;
    return v.f;
}

// ---------------- CSR build ----------------

__global__ void hist_kernel(const int* __restrict__ dst, int* __restrict__ count, int E) {
    int i = blockIdx.x * blockDim.x + threadIdx.x;
    if (i < E) atomicAdd(&count[dst[i]], 1);
}

__global__ void scan1_kernel(const int* __restrict__ count, int* __restrict__ bsums, int N) {
    __shared__ int s[256];
    int t = threadIdx.x, i = blockIdx.x * 256 + t;
    int v = (i < N) ? count[i] : 0;
    s[t] = v; __syncthreads();
    for (int o = 1; o < 256; o <<= 1) {
        int x = (t >= o) ? s[t - o] : 0;
        __syncthreads(); s[t] += x; __syncthreads();
    }
    if (t == 255) bsums[blockIdx.x] = s[255];
}

__global__ void scan2_kernel(int* __restrict__ bsums, int nb) {
    __shared__ int s[256];
    int t = threadIdx.x;
    int v = (t < nb) ? bsums[t] : 0;
    s[t] = v; __syncthreads();
    for (int o = 1; o < 256; o <<= 1) {
        int x = (t >= o) ? s[t - o] : 0;
        __syncthreads(); s[t] += x; __syncthreads();
    }
    if (t < nb) bsums[t] = s[t] - v;
}

__global__ void scan3_kernel(const int* __restrict__ count, const int* __restrict__ bsums,
                             int* __restrict__ rowptr, int* __restrict__ cursor,
                             float* __restrict__ dinv, int N, int E) {
    __shared__ int s[256];
    int t = threadIdx.x, i = blockIdx.x * 256 + t;
    int v = (i < N) ? count[i] : 0;
    s[t] = v; __syncthreads();
    for (int o = 1; o < 256; o <<= 1) {
        int x = (t >= o) ? s[t - o] : 0;
        __syncthreads(); s[t] += x; __syncthreads();
    }
    if (i < N) {
        int ex = bsums[blockIdx.x] + s[t] - v;
        rowptr[i] = ex;
        cursor[i] = ex;
        dinv[i] = rsqrtf((float)v + 1.0f);
        if (i == 0) rowptr[N] = E;
    }
}

__global__ void scatter_kernel(const int* __restrict__ src, const int* __restrict__ dst,
                               int* __restrict__ cursor, int* __restrict__ csr, int E) {
    int e = blockIdx.x * blockDim.x + threadIdx.x;
    if (e < E) {
        int p = atomicAdd(&cursor[dst[e]], 1);
        csr[p] = src[e];
    }
}

// ---------------- W prep: K x N f32 row-major -> N x K bf16 hi/lo ----------------

__global__ void wprep_kernel(const float* __restrict__ W, short* __restrict__ hi,
                             short* __restrict__ lo, int K, int N) {
    int i = blockIdx.x * blockDim.x + threadIdx.x;
    if (i >= K * N) return;
    int k = i / N, n = i % N;
    float w = W[i];
    short h = f2bf(w);
    hi[n * K + k] = h;
    lo[n * K + k] = f2bf(w - bf2f(h));
}

// ---------------- split-bf16 MFMA GEMM ----------------
// C[M,N] = A[M,K] @ B[K,N], B given transposed+split (Bth/Btl: N x K bf16).
// Block = 256 thr (4 waves), 64 rows/block (16 rows/wave), full N per wave.
// C/D layout (16x16x32): col = lane&15, row = (lane>>4)*4 + reg [verified m89/m91].
// A frag: A[m=lane&15][k = (lane>>4)*8 + j].  B frag: Bt[n=lane&15][k likewise].

template <int K, int N, bool RELU>
__launch_bounds__(256)
__global__ void gemm_mfma_kernel(const float* __restrict__ A,
                                 const short* __restrict__ Bth,
                                 const short* __restrict__ Btl,
                                 const float* __restrict__ bias,
                                 float* __restrict__ C, int M) {
    constexpr int NT = N / 16;
    const int lane = threadIdx.x & 63;
    const int wave = threadIdx.x >> 6;
    const int row0 = blockIdx.x * 64 + wave * 16;
    const int am = row0 + (lane & 15);
    const int kq = (lane >> 4) * 8;
    const int bn = lane & 15;

    f32x4 acc[NT];
#pragma unroll
    for (int t = 0; t < NT; ++t) acc[t] = f32x4{0.f, 0.f, 0.f, 0.f};

    const float* arow = A + (size_t)(am < M ? am : M - 1) * K;

    for (int kb = 0; kb < K; kb += 32) {
        float4 a0 = *(const float4*)(arow + kb + kq);
        float4 a1 = *(const float4*)(arow + kb + kq + 4);
        float av[8] = {a0.x, a0.y, a0.z, a0.w, a1.x, a1.y, a1.z, a1.w};
        bf16x8 ah, al;
#pragma unroll
        for (int j = 0; j < 8; ++j) {
            short h = f2bf(av[j]);
            ah[j] = h;
            al[j] = f2bf(av[j] - bf2f(h));
        }
#pragma unroll
        for (int t = 0; t < NT; ++t) {
            size_t boff = (size_t)(t * 16 + bn) * K + kb + kq;
            bf16x8 bh = *(const bf16x8*)(Bth + boff);
            bf16x8 bl = *(const bf16x8*)(Btl + boff);
            acc[t] = __builtin_amdgcn_mfma_f32_16x16x32_bf16(ah, bh, acc[t], 0, 0, 0);
            acc[t] = __builtin_amdgcn_mfma_f32_16x16x32_bf16(ah, bl, acc[t], 0, 0, 0);
            acc[t] = __builtin_amdgcn_mfma_f32_16x16x32_bf16(al, bh, acc[t], 0, 0, 0);
        }
    }

    const int cr0 = row0 + (lane >> 4) * 4;
#pragma unroll
    for (int t = 0; t < NT; ++t) {
        int col = t * 16 + bn;
        float bv = RELU ? bias[col] : 0.f;
#pragma unroll
        for (int r = 0; r < 4; ++r) {
            int rr = cr0 + r;
            if (rr < M) {
                float v = acc[t][r];
                if (RELU) v = fmaxf(v + bv, 0.f);
                C[(size_t)rr * N + col] = v;
            }
        }
    }
}

// ---------------- gather aggregation (one wave per dst node, D=128) ----------------
// out[d] = [relu]( sum_{j in row d} h[csr[j]]*dinv[csr[j]]*dinv[d] + h[d]*dinv[d]^2 [+ bias] )

template <bool BR>
__launch_bounds__(256)
__global__ void agg_gather_kernel(const float* __restrict__ h, const float* __restrict__ dinv,
                                  const int* __restrict__ rowptr, const int* __restrict__ csr,
                                  const float* __restrict__ bias, float* __restrict__ out, int N) {
    int wid = (blockIdx.x * blockDim.x + threadIdx.x) >> 6;  // node id
    int lane = threadIdx.x & 63;
    if (wid >= N) return;
    int lo = rowptr[wid], hi = rowptr[wid + 1];
    float dd = dinv[wid];

    const float2* hp = (const float2*)h;           // 64 float2 per row (D=128)
    float2 acc = hp[(size_t)wid * 64 + lane];
    float sc = dd * dd;
    acc.x *= sc; acc.y *= sc;
    for (int j = lo; j < hi; ++j) {
        int s = csr[j];
        float nm = dinv[s] * dd;
        float2 v = hp[(size_t)s * 64 + lane];
        acc.x = fmaf(v.x, nm, acc.x);
        acc.y = fmaf(v.y, nm, acc.y);
    }
    if (BR) {
        float2 b = ((const float2*)bias)[lane];
        acc.x = fmaxf(acc.x + b.x, 0.f);
        acc.y = fmaxf(acc.y + b.y, 0.f);
    }
    ((float2*)out)[(size_t)wid * 64 + lane] = acc;
}

// ---------------- pool + fc ----------------

__launch_bounds__(128)
__global__ void pool_kernel(const float* __restrict__ h, const int* __restrict__ batch,
                            float* __restrict__ pool, int N) {
    int c = threadIdx.x;              // dim 0..127
    int i0 = blockIdx.x * PCH;
    if (i0 >= N) return;
    int i1 = min(i0 + PCH, N);
    int g = batch[i0];
    float acc = 0.f;
#pragma unroll 4
    for (int i = i0; i < i1; ++i) {
        int gi = batch[i];
        if (gi != g) {                // wave-uniform branch
            atomicAdd(&pool[g * HID2 + c], acc);
            acc = 0.f; g = gi;
        }
        acc += h[(size_t)i * HID2 + c];
    }
    atomicAdd(&pool[g * HID2 + c], acc);
}

__device__ __forceinline__ int lower_bound_i(const int* __restrict__ a, int n, int key) {
    int lo = 0, hi = n;
    while (lo < hi) {
        int mid = (lo + hi) >> 1;
        if (a[mid] < key) lo = mid + 1; else hi = mid;
    }
    return lo;
}

__global__ void fc_kernel(const float* __restrict__ pool, const int* __restrict__ batch,
                          const float* __restrict__ Wfc, const float* __restrict__ bfc,
                          float* __restrict__ out, int N) {
    int t = threadIdx.x;  // 256 = 64 graphs * 4 outputs
    int g = t >> 2, o = t & 3;
    int lo = lower_bound_i(batch, N, g);
    int hi = lower_bound_i(batch, N, g + 1);
    float acc = 0.f;
#pragma unroll 8
    for (int c = 0; c < HID2; ++c)
        acc = fmaf(pool[g * HID2 + c], Wfc[c * OUT_DIM + o], acc);
    float inv = 1.0f / fmaxf((float)(hi - lo), 1.0f);
    out[g * OUT_DIM + o] = acc * inv + bfc[o];
}

extern "C" void kernel_launch(void* const* d_in, const int* in_sizes, int n_in,
                              void* d_out, int out_size, void* d_ws, size_t ws_size,
                              hipStream_t stream) {
    const float* x   = (const float*)d_in[0];
    const int* src   = (const int*)d_in[1];
    const int* dst   = (const int*)d_in[2];
    const int* batch = (const int*)d_in[3];
    const float* W1  = (const float*)d_in[4];
    const float* b1  = (const float*)d_in[5];
    const float* W2  = (const float*)d_in[6];
    const float* b2  = (const float*)d_in[7];
    const float* Wfc = (const float*)d_in[8];
    const float* bfc = (const float*)d_in[9];
    float* out = (float*)d_out;

    const int N = in_sizes[0] / IN_DIM;  // 50000
    const int E = in_sizes[1];           // 640000
    const int NB = (N + 255) / 256;      // scan blocks (196)

    // ---- workspace layout ----
    char* ws = (char*)d_ws;
    size_t off = 0;
    auto alloc = [&](size_t bytes) {
        char* p = ws + off;
        off = (off + bytes + 255) & ~(size_t)255;
        return p;
    };
    float* dinv   = (float*)alloc((size_t)N * 4);
    int*   count  = (int*)  alloc((size_t)N * 4);
    int*   cursor = (int*)  alloc((size_t)N * 4);
    int*   rowptr = (int*)  alloc((size_t)(N + 1) * 4);
    int*   bsums  = (int*)  alloc(256 * 4);
    int*   csr    = (int*)  alloc((size_t)E * 4);
    short* W1th   = (short*)alloc((size_t)IN_DIM * HID * 2);
    short* W1tl   = (short*)alloc((size_t)IN_DIM * HID * 2);
    short* W2th   = (short*)alloc((size_t)HID * HID2 * 2);
    short* W2tl   = (short*)alloc((size_t)HID * HID2 * 2);
    float* ax     = (float*)alloc((size_t)N * HID2 * 4);  // A·x ; reused as h2
    float* a1     = (float*)alloc((size_t)N * HID * 4);   // relu(ax@W1+b1); a2 reuses
    float* pool   = (float*)alloc((size_t)NGRAPH * HID2 * 4);
    float* h2 = ax;     // ax dead after gemm1
    float* a2 = a1;     // a1 dead after gemm2

    // ---- CSR build (once; serves both layers) ----
    hipMemsetAsync(count, 0, (size_t)N * 4, stream);
    hist_kernel<<<(E + 255) / 256, 256, 0, stream>>>(dst, count, E);
    scan1_kernel<<<NB, 256, 0, stream>>>(count, bsums, N);
    scan2_kernel<<<1, 256, 0, stream>>>(bsums, NB);
    scan3_kernel<<<NB, 256, 0, stream>>>(count, bsums, rowptr, cursor, dinv, N, E);
    scatter_kernel<<<(E + 255) / 256, 256, 0, stream>>>(src, dst, cursor, csr, E);

    // ---- weight prep (independent of CSR) ----
    wprep_kernel<<<(IN_DIM * HID + 255) / 256, 256, 0, stream>>>(W1, W1th, W1tl, IN_DIM, HID);
    wprep_kernel<<<(HID * HID2 + 255) / 256, 256, 0, stream>>>(W2, W2th, W2tl, HID, HID2);

    // ---- layer 1: aggregate first (linearity), then GEMM with fused bias+relu ----
    agg_gather_kernel<false><<<(N + 3) / 4, 256, 0, stream>>>(x, dinv, rowptr, csr, nullptr, ax, N);
    gemm_mfma_kernel<IN_DIM, HID, true><<<(N + 63) / 64, 256, 0, stream>>>(
        ax, W1th, W1tl, b1, a1, N);

    // ---- layer 2: GEMM then aggregate with fused bias+relu ----
    gemm_mfma_kernel<HID, HID2, false><<<(N + 63) / 64, 256, 0, stream>>>(
        a1, W2th, W2tl, nullptr, h2, N);
    agg_gather_kernel<true><<<(N + 3) / 4, 256, 0, stream>>>(h2, dinv, rowptr, csr, b2, a2, N);

    // ---- pool + fc ----
    hipMemsetAsync(pool, 0, (size_t)NGRAPH * HID2 * 4, stream);
    pool_kernel<<<(N + PCH - 1) / PCH, HID2, 0, stream>>>(a2, batch, pool, N);
    fc_kernel<<<1, NGRAPH * OUT_DIM, 0, stream>>>(pool, batch, Wfc, bfc, out, N);
}

// Round 6
// 403.864 us; speedup vs baseline: 1.1896x; 1.1896x over previous
//
#include <hip/hip_runtime.h>

// GCN forward. Linearity reorder + split-bf16 LDS-tiled MFMA GEMMs.
//   ax  = A·x                    (agg D=128, writes bf16 hi/lo)
//   a1  = relu(ax@W1 + b1)       (MFMA GEMM, writes bf16 hi/lo)
//   h2  = a1@W2                  (MFMA GEMM, writes f32)
//   a2  = relu(A·h2 + b2)        (agg D=128, f32)
//   out = meanpool(a2)@Wfc + bfc
// f32 GEMM emulated as bf16 hi/lo split: hi*hi + hi*lo + lo*hi (drop lo*lo ~2^-16 rel).
// GEMM: 128x128 block tile, 4 waves x (64x64), BK=32, fragment-ordered LDS slabs,
// register-staged (global 16B load -> ds_write_b128). No global_load_lds (r5 suspect).

constexpr int IN_DIM  = 128;
constexpr int HID     = 256;
constexpr int HID2    = 128;
constexpr int OUT_DIM = 4;
constexpr int NGRAPH  = 64;
constexpr int PCH     = 64;   // nodes per pool block

typedef __attribute__((ext_vector_type(8))) short bf16x8;
typedef __attribute__((ext_vector_type(4))) float f32x4;

__device__ __forceinline__ short f2bf(float f) {
    union { float f; unsigned u; } v; v.f = f;
    unsigned r = v.u + 0x7fff + ((v.u >> 16) & 1);   // RNE
    return (short)(r >> 16);
}
__device__ __forceinline__ float bf2f(short s) {
    union { unsigned u; float f; } v; v.u = ((unsigned)(unsigned short)s) << 16;
    return v.f;
}

// ---------------- CSR build ----------------

__global__ void hist_kernel(const int* __restrict__ dst, int* __restrict__ count, int E) {
    int i = blockIdx.x * blockDim.x + threadIdx.x;
    if (i < E) atomicAdd(&count[dst[i]], 1);
}

__global__ void scan1_kernel(const int* __restrict__ count, int* __restrict__ bsums, int N) {
    __shared__ int s[256];
    int t = threadIdx.x, i = blockIdx.x * 256 + t;
    int v = (i < N) ? count[i] : 0;
    s[t] = v; __syncthreads();
    for (int o = 1; o < 256; o <<= 1) {
        int x = (t >= o) ? s[t - o] : 0;
        __syncthreads(); s[t] += x; __syncthreads();
    }
    if (t == 255) bsums[blockIdx.x] = s[255];
}

__global__ void scan2_kernel(int* __restrict__ bsums, int nb) {
    __shared__ int s[256];
    int t = threadIdx.x;
    int v = (t < nb) ? bsums[t] : 0;
    s[t] = v; __syncthreads();
    for (int o = 1; o < 256; o <<= 1) {
        int x = (t >= o) ? s[t - o] : 0;
        __syncthreads(); s[t] += x; __syncthreads();
    }
    if (t < nb) bsums[t] = s[t] - v;
}

__global__ void scan3_kernel(const int* __restrict__ count, const int* __restrict__ bsums,
                             int* __restrict__ rowptr, int* __restrict__ cursor,
                             float* __restrict__ dinv, int N, int E) {
    __shared__ int s[256];
    int t = threadIdx.x, i = blockIdx.x * 256 + t;
    int v = (i < N) ? count[i] : 0;
    s[t] = v; __syncthreads();
    for (int o = 1; o < 256; o <<= 1) {
        int x = (t >= o) ? s[t - o] : 0;
        __syncthreads(); s[t] += x; __syncthreads();
    }
    if (i < N) {
        int ex = bsums[blockIdx.x] + s[t] - v;
        rowptr[i] = ex;
        cursor[i] = ex;
        dinv[i] = rsqrtf((float)v + 1.0f);
        if (i == 0) rowptr[N] = E;
    }
}

__global__ void scatter_kernel(const int* __restrict__ src, const int* __restrict__ dst,
                               int* __restrict__ cursor, int* __restrict__ csr, int E) {
    int e = blockIdx.x * blockDim.x + threadIdx.x;
    if (e < E) {
        int p = atomicAdd(&cursor[dst[e]], 1);
        csr[p] = src[e];
    }
}

// ---------------- W prep: K x N f32 row-major -> N x K bf16 hi/lo ----------------

__global__ void wprep_kernel(const float* __restrict__ W, short* __restrict__ hi,
                             short* __restrict__ lo, int K, int N) {
    int i = blockIdx.x * blockDim.x + threadIdx.x;
    if (i >= K * N) return;
    int k = i / N, n = i % N;
    float w = W[i];
    short h = f2bf(w);
    hi[n * K + k] = h;
    lo[n * K + k] = f2bf(w - bf2f(h));
}

// ---------------- split-bf16 LDS-tiled MFMA GEMM ----------------
// C[M,N] = (Ah+Al)[M,K] @ (Bh+Bl)^T  with B given as N x K (transposed).
// Block: 128 rows x 128 cols, 256 thr. Wave w: staging role (Ah/Al/Bh/Bl),
// compute microtile mt=(w&1)*4, nt=(w>>1)*4.
// LDS slab = one 16x32 tile in MFMA fragment order: lane*16B holds
// (row = lane&15, k-span = (lane>>4)*8). Reads back as single ds_read_b128.
// C/D layout (16x16x32): col = lane&15, row = (lane>>4)*4 + reg [verified m89/m91].

template <int K, int N, bool RELU, bool OBF16>
__launch_bounds__(256)
__global__ void gemm_tile_kernel(const short* __restrict__ Ah, const short* __restrict__ Al,
                                 const short* __restrict__ Bh, const short* __restrict__ Bl,
                                 const float* __restrict__ bias,
                                 float* __restrict__ C, short* __restrict__ Ch,
                                 short* __restrict__ Cl, int M) {
    __shared__ __align__(16) short S[4][8][512];   // [Ah|Al|Bh|Bl][tile][frag] = 32 KB

    const int tid  = threadIdx.x;
    const int wave = tid >> 6;
    const int lane = tid & 63;
    const int row0 = blockIdx.y * 128;
    const int col0 = blockIdx.x * 128;

    // staging role: wave 0 -> A-hi, 1 -> A-lo, 2 -> B-hi, 3 -> B-lo (8 slabs each)
    const short* gsrc = (wave == 0) ? Ah : (wave == 1) ? Al : (wave == 2) ? Bh : Bl;
    const bool isA = wave < 2;
    const int rbase = (isA ? row0 : col0) + (lane & 15);
    const int kq = (lane >> 4) * 8;

    f32x4 acc[4][4];
#pragma unroll
    for (int i = 0; i < 4; ++i)
#pragma unroll
        for (int j = 0; j < 4; ++j) acc[i][j] = f32x4{0.f, 0.f, 0.f, 0.f};

    const int mt0 = (wave & 1) * 4;
    const int nt0 = (wave >> 1) * 4;

    for (int kb = 0; kb < K; kb += 32) {
        // stage: 8 slabs per wave, one 16B chunk per lane per slab
        bf16x8 stg[8];
#pragma unroll
        for (int j = 0; j < 8; ++j) {
            int rr = rbase + j * 16;
            if (isA && rr >= M) rr = M - 1;           // clamp tail rows (stores guarded)
            stg[j] = *(const bf16x8*)(gsrc + (size_t)rr * K + kb + kq);
        }
#pragma unroll
        for (int j = 0; j < 8; ++j)
            *(bf16x8*)&S[wave][j][lane * 8] = stg[j];
        __syncthreads();

        bf16x8 ah[4], al[4], bh[4], bl[4];
#pragma unroll
        for (int i = 0; i < 4; ++i) {
            ah[i] = *(const bf16x8*)&S[0][mt0 + i][lane * 8];
            al[i] = *(const bf16x8*)&S[1][mt0 + i][lane * 8];
            bh[i] = *(const bf16x8*)&S[2][nt0 + i][lane * 8];
            bl[i] = *(const bf16x8*)&S[3][nt0 + i][lane * 8];
        }
#pragma unroll
        for (int i = 0; i < 4; ++i)
#pragma unroll
            for (int j = 0; j < 4; ++j) {
                acc[i][j] = __builtin_amdgcn_mfma_f32_16x16x32_bf16(ah[i], bh[j], acc[i][j], 0, 0, 0);
                acc[i][j] = __builtin_amdgcn_mfma_f32_16x16x32_bf16(ah[i], bl[j], acc[i][j], 0, 0, 0);
                acc[i][j] = __builtin_amdgcn_mfma_f32_16x16x32_bf16(al[i], bh[j], acc[i][j], 0, 0, 0);
            }
        __syncthreads();
    }

    // epilogue
    const int crow = (lane >> 4) * 4;
    const int ccol = lane & 15;
#pragma unroll
    for (int j = 0; j < 4; ++j) {
        int col = col0 + (nt0 + j) * 16 + ccol;
        float bv = RELU ? bias[col] : 0.f;
#pragma unroll
        for (int i = 0; i < 4; ++i) {
#pragma unroll
            for (int r = 0; r < 4; ++r) {
                int row = row0 + (mt0 + i) * 16 + crow + r;
                if (row < M) {
                    float v = acc[i][j][r];
                    if (RELU) v = fmaxf(v + bv, 0.f);
                    if (OBF16) {
                        short h = f2bf(v);
                        Ch[(size_t)row * N + col] = h;
                        Cl[(size_t)row * N + col] = f2bf(v - bf2f(h));
                    } else {
                        C[(size_t)row * N + col] = v;
                    }
                }
            }
        }
    }
}

// ---------------- gather aggregation (one wave per dst node, D=128) ----------------
// out[d] = [relu]( sum_{j in row d} h[csr[j]]*dinv[csr[j]]*dinv[d] + h[d]*dinv[d]^2 [+bias] )

template <bool BR, bool OBF16>
__launch_bounds__(256)
__global__ void agg_gather_kernel(const float* __restrict__ h, const float* __restrict__ dinv,
                                  const int* __restrict__ rowptr, const int* __restrict__ csr,
                                  const float* __restrict__ bias, float* __restrict__ out,
                                  short* __restrict__ oh, short* __restrict__ ol, int N) {
    int wid = (blockIdx.x * blockDim.x + threadIdx.x) >> 6;  // node id
    int lane = threadIdx.x & 63;
    if (wid >= N) return;
    int lo = rowptr[wid], hi = rowptr[wid + 1];
    float dd = dinv[wid];

    const float2* hp = (const float2*)h;           // 64 float2 per row (D=128)
    float2 acc = hp[(size_t)wid * 64 + lane];
    float sc = dd * dd;
    acc.x *= sc; acc.y *= sc;
    for (int j = lo; j < hi; ++j) {
        int s = csr[j];
        float nm = dinv[s] * dd;
        float2 v = hp[(size_t)s * 64 + lane];
        acc.x = fmaf(v.x, nm, acc.x);
        acc.y = fmaf(v.y, nm, acc.y);
    }
    if (BR) {
        float2 b = ((const float2*)bias)[lane];
        acc.x = fmaxf(acc.x + b.x, 0.f);
        acc.y = fmaxf(acc.y + b.y, 0.f);
    }
    if (OBF16) {
        short hx = f2bf(acc.x), hy = f2bf(acc.y);
        short2 hv; hv.x = hx; hv.y = hy;
        short2 lv; lv.x = f2bf(acc.x - bf2f(hx)); lv.y = f2bf(acc.y - bf2f(hy));
        *(short2*)&oh[(size_t)wid * 128 + lane * 2] = hv;
        *(short2*)&ol[(size_t)wid * 128 + lane * 2] = lv;
    } else {
        ((float2*)out)[(size_t)wid * 64 + lane] = acc;
    }
}

// ---------------- pool + fc ----------------

__launch_bounds__(128)
__global__ void pool_kernel(const float* __restrict__ h, const int* __restrict__ batch,
                            float* __restrict__ pool, int N) {
    int c = threadIdx.x;              // dim 0..127
    int i0 = blockIdx.x * PCH;
    if (i0 >= N) return;
    int i1 = min(i0 + PCH, N);
    int g = batch[i0];
    float acc = 0.f;
#pragma unroll 4
    for (int i = i0; i < i1; ++i) {
        int gi = batch[i];
        if (gi != g) {                // wave-uniform branch
            atomicAdd(&pool[g * HID2 + c], acc);
            acc = 0.f; g = gi;
        }
        acc += h[(size_t)i * HID2 + c];
    }
    atomicAdd(&pool[g * HID2 + c], acc);
}

__device__ __forceinline__ int lower_bound_i(const int* __restrict__ a, int n, int key) {
    int lo = 0, hi = n;
    while (lo < hi) {
        int mid = (lo + hi) >> 1;
        if (a[mid] < key) lo = mid + 1; else hi = mid;
    }
    return lo;
}

__global__ void fc_kernel(const float* __restrict__ pool, const int* __restrict__ batch,
                          const float* __restrict__ Wfc, const float* __restrict__ bfc,
                          float* __restrict__ out, int N) {
    int t = threadIdx.x;  // 256 = 64 graphs * 4 outputs
    int g = t >> 2, o = t & 3;
    int lo = lower_bound_i(batch, N, g);
    int hi = lower_bound_i(batch, N, g + 1);
    float acc = 0.f;
#pragma unroll 8
    for (int c = 0; c < HID2; ++c)
        acc = fmaf(pool[g * HID2 + c], Wfc[c * OUT_DIM + o], acc);
    float inv = 1.0f / fmaxf((float)(hi - lo), 1.0f);
    out[g * OUT_DIM + o] = acc * inv + bfc[o];
}

extern "C" void kernel_launch(void* const* d_in, const int* in_sizes, int n_in,
                              void* d_out, int out_size, void* d_ws, size_t ws_size,
                              hipStream_t stream) {
    const float* x   = (const float*)d_in[0];
    const int* src   = (const int*)d_in[1];
    const int* dst   = (const int*)d_in[2];
    const int* batch = (const int*)d_in[3];
    const float* W1  = (const float*)d_in[4];
    const float* b1  = (const float*)d_in[5];
    const float* W2  = (const float*)d_in[6];
    const float* b2  = (const float*)d_in[7];
    const float* Wfc = (const float*)d_in[8];
    const float* bfc = (const float*)d_in[9];
    float* out = (float*)d_out;

    const int N = in_sizes[0] / IN_DIM;  // 50000
    const int E = in_sizes[1];           // 640000
    const int NB = (N + 255) / 256;      // scan blocks (196)

    // ---- workspace layout (~81 MB; region X/Y aliasing) ----
    char* ws = (char*)d_ws;
    size_t off = 0;
    auto alloc = [&](size_t bytes) {
        char* p = ws + off;
        off = (off + bytes + 255) & ~(size_t)255;
        return p;
    };
    float* dinv   = (float*)alloc((size_t)N * 4);
    int*   count  = (int*)  alloc((size_t)N * 4);
    int*   cursor = (int*)  alloc((size_t)N * 4);
    int*   rowptr = (int*)  alloc((size_t)(N + 1) * 4);
    int*   bsums  = (int*)  alloc(256 * 4);
    int*   csr    = (int*)  alloc((size_t)E * 4);
    short* W1th   = (short*)alloc((size_t)IN_DIM * HID * 2);
    short* W1tl   = (short*)alloc((size_t)IN_DIM * HID * 2);
    short* W2th   = (short*)alloc((size_t)HID * HID2 * 2);
    short* W2tl   = (short*)alloc((size_t)HID * HID2 * 2);
    // region X (25.6 MB): axh/axl -> later h2 (f32)
    short* axh    = (short*)alloc((size_t)N * IN_DIM * 2);
    short* axl    = (short*)alloc((size_t)N * IN_DIM * 2);
    // region Y (51.2 MB): a1h/a1l -> later a2 (f32, first half)
    short* a1h    = (short*)alloc((size_t)N * HID * 2);
    short* a1l    = (short*)alloc((size_t)N * HID * 2);
    float* pool   = (float*)alloc((size_t)NGRAPH * HID2 * 4);
    float* h2 = (float*)axh;     // ax dead after gemm1
    float* a2 = (float*)a1h;     // a1 dead after gemm2

    // ---- CSR build (once; serves both layers) ----
    hipMemsetAsync(count, 0, (size_t)N * 4, stream);
    hist_kernel<<<(E + 255) / 256, 256, 0, stream>>>(dst, count, E);
    scan1_kernel<<<NB, 256, 0, stream>>>(count, bsums, N);
    scan2_kernel<<<1, 256, 0, stream>>>(bsums, NB);
    scan3_kernel<<<NB, 256, 0, stream>>>(count, bsums, rowptr, cursor, dinv, N, E);
    scatter_kernel<<<(E + 255) / 256, 256, 0, stream>>>(src, dst, cursor, csr, E);

    // ---- weight prep ----
    wprep_kernel<<<(IN_DIM * HID + 255) / 256, 256, 0, stream>>>(W1, W1th, W1tl, IN_DIM, HID);
    wprep_kernel<<<(HID * HID2 + 255) / 256, 256, 0, stream>>>(W2, W2th, W2tl, HID, HID2);

    // ---- layer 1: aggregate (writes bf16 hi/lo), then GEMM w/ fused bias+relu+split ----
    agg_gather_kernel<false, true><<<(N + 3) / 4, 256, 0, stream>>>(
        x, dinv, rowptr, csr, nullptr, nullptr, axh, axl, N);
    gemm_tile_kernel<IN_DIM, HID, true, true><<<dim3(HID / 128, (N + 127) / 128), 256, 0, stream>>>(
        axh, axl, W1th, W1tl, b1, nullptr, a1h, a1l, N);

    // ---- layer 2: GEMM (f32 out), then aggregate w/ fused bias+relu ----
    gemm_tile_kernel<HID, HID2, false, false><<<dim3(HID2 / 128, (N + 127) / 128), 256, 0, stream>>>(
        a1h, a1l, W2th, W2tl, nullptr, h2, nullptr, nullptr, N);
    agg_gather_kernel<true, false><<<(N + 3) / 4, 256, 0, stream>>>(
        h2, dinv, rowptr, csr, b2, a2, nullptr, nullptr, N);

    // ---- pool + fc ----
    hipMemsetAsync(pool, 0, (size_t)NGRAPH * HID2 * 4, stream);
    pool_kernel<<<(N + PCH - 1) / PCH, HID2, 0, stream>>>(a2, batch, pool, N);
    fc_kernel<<<1, NGRAPH * OUT_DIM, 0, stream>>>(pool, batch, Wfc, bfc, out, N);
}

// Round 7
// 369.496 us; speedup vs baseline: 1.3002x; 1.0930x over previous
//
#include <hip/hip_runtime.h>

// GCN forward. Linearity reorder + split-bf16 MFMA GEMMs + bf16 pre-scaled gathers.
//   xb  = bf16(x * dinv_row)          (scale_cast)
//   ax  = dd*Σ xb[s] + dd²*x[d]       (agg1, bf16 gathers, writes bf16 hi/lo)
//   a1  = relu(ax@W1 + b1)            (MFMA GEMM, writes bf16 hi/lo)
//   h2  = a1@W2                       (MFMA GEMM, writes f32 + bf16(h2*dinv))
//   a2  = relu(dd*Σ h2b[s] + dd²*h2[d] + b2)   (agg2)
//   out = meanpool(a2)@Wfc + bfc
// f32 GEMM emulated as bf16 hi/lo split: hi*hi + hi*lo + lo*hi (~2^-16 rel).
// bf16 gathers halve agg fetch traffic; dinv[src] folded into the gathered table
// so the per-edge chain is csr-index -> row gather only (indices wave-broadcast).

constexpr int IN_DIM  = 128;
constexpr int HID     = 256;
constexpr int HID2    = 128;
constexpr int OUT_DIM = 4;
constexpr int NGRAPH  = 64;
constexpr int PCH     = 64;   // nodes per pool block

typedef __attribute__((ext_vector_type(8))) short bf16x8;
typedef __attribute__((ext_vector_type(4))) float f32x4;

__device__ __forceinline__ short f2bf(float f) {
    union { float f; unsigned u; } v; v.f = f;
    unsigned r = v.u + 0x7fff + ((v.u >> 16) & 1);   // RNE
    return (short)(r >> 16);
}
__device__ __forceinline__ float bf2f(short s) {
    union { unsigned u; float f; } v; v.u = ((unsigned)(unsigned short)s) << 16;
    return v.f;
}

// ---------------- CSR build ----------------

__global__ void hist_kernel(const int* __restrict__ dst, int* __restrict__ count, int E) {
    int i = blockIdx.x * blockDim.x + threadIdx.x;
    if (i < E) atomicAdd(&count[dst[i]], 1);
}

__global__ void scan1_kernel(const int* __restrict__ count, int* __restrict__ bsums, int N) {
    __shared__ int s[256];
    int t = threadIdx.x, i = blockIdx.x * 256 + t;
    int v = (i < N) ? count[i] : 0;
    s[t] = v; __syncthreads();
    for (int o = 1; o < 256; o <<= 1) {
        int x = (t >= o) ? s[t - o] : 0;
        __syncthreads(); s[t] += x; __syncthreads();
    }
    if (t == 255) bsums[blockIdx.x] = s[255];
}

__global__ void scan2_kernel(int* __restrict__ bsums, int nb) {
    __shared__ int s[256];
    int t = threadIdx.x;
    int v = (t < nb) ? bsums[t] : 0;
    s[t] = v; __syncthreads();
    for (int o = 1; o < 256; o <<= 1) {
        int x = (t >= o) ? s[t - o] : 0;
        __syncthreads(); s[t] += x; __syncthreads();
    }
    if (t < nb) bsums[t] = s[t] - v;
}

__global__ void scan3_kernel(const int* __restrict__ count, const int* __restrict__ bsums,
                             int* __restrict__ rowptr, int* __restrict__ cursor,
                             float* __restrict__ dinv, int N, int E) {
    __shared__ int s[256];
    int t = threadIdx.x, i = blockIdx.x * 256 + t;
    int v = (i < N) ? count[i] : 0;
    s[t] = v; __syncthreads();
    for (int o = 1; o < 256; o <<= 1) {
        int x = (t >= o) ? s[t - o] : 0;
        __syncthreads(); s[t] += x; __syncthreads();
    }
    if (i < N) {
        int ex = bsums[blockIdx.x] + s[t] - v;
        rowptr[i] = ex;
        cursor[i] = ex;
        dinv[i] = rsqrtf((float)v + 1.0f);
        if (i == 0) rowptr[N] = E;
    }
}

__global__ void scatter_kernel(const int* __restrict__ src, const int* __restrict__ dst,
                               int* __restrict__ cursor, int* __restrict__ csr, int E) {
    int e = blockIdx.x * blockDim.x + threadIdx.x;
    if (e < E) {
        int p = atomicAdd(&cursor[dst[e]], 1);
        csr[p] = src[e];
    }
}

// ---------------- W prep: K x N f32 row-major -> N x K bf16 hi/lo ----------------

__global__ void wprep_kernel(const float* __restrict__ W, short* __restrict__ hi,
                             short* __restrict__ lo, int K, int N) {
    int i = blockIdx.x * blockDim.x + threadIdx.x;
    if (i >= K * N) return;
    int k = i / N, n = i % N;
    float w = W[i];
    short h = f2bf(w);
    hi[n * K + k] = h;
    lo[n * K + k] = f2bf(w - bf2f(h));
}

// ---------------- xb = bf16(x * dinv_row) ----------------

__global__ void scale_cast_kernel(const float* __restrict__ x, const float* __restrict__ dinv,
                                  ushort* __restrict__ xb, int total2) {
    int i = blockIdx.x * blockDim.x + threadIdx.x;   // float2 granularity, 64 per node
    if (i >= total2) return;
    float d = dinv[i >> 6];
    float2 v = ((const float2*)x)[i];
    ushort2 o;
    o.x = (ushort)f2bf(v.x * d);
    o.y = (ushort)f2bf(v.y * d);
    ((ushort2*)xb)[i] = o;
}

// ---------------- split-bf16 LDS-tiled MFMA GEMM ----------------
// C[M,N] = (Ah+Al)[M,K] @ (Bh+Bl)^T  with B given as N x K (transposed).
// Block: 128 rows x 128 cols, 256 thr. Wave w: staging role (Ah/Al/Bh/Bl),
// compute microtile mt=(w&1)*4, nt=(w>>1)*4.
// LDS slab = one 16x32 tile in MFMA fragment order (single ds_read_b128 reads).
// C/D layout (16x16x32): col = lane&15, row = (lane>>4)*4 + reg [verified m89/m91].
// OBF16: write bf16 hi/lo split.  SCB16: write f32 C AND Cb=bf16(v*dinv[row]).

template <int K, int N, bool RELU, bool OBF16, bool SCB16>
__launch_bounds__(256)
__global__ void gemm_tile_kernel(const short* __restrict__ Ah, const short* __restrict__ Al,
                                 const short* __restrict__ Bh, const short* __restrict__ Bl,
                                 const float* __restrict__ bias,
                                 float* __restrict__ C, short* __restrict__ Ch,
                                 short* __restrict__ Cl,
                                 const float* __restrict__ dinv, ushort* __restrict__ Cb,
                                 int M) {
    __shared__ __align__(16) short S[4][8][512];   // [Ah|Al|Bh|Bl][tile][frag] = 32 KB

    const int tid  = threadIdx.x;
    const int wave = tid >> 6;
    const int lane = tid & 63;
    const int row0 = blockIdx.y * 128;
    const int col0 = blockIdx.x * 128;

    const short* gsrc = (wave == 0) ? Ah : (wave == 1) ? Al : (wave == 2) ? Bh : Bl;
    const bool isA = wave < 2;
    const int rbase = (isA ? row0 : col0) + (lane & 15);
    const int kq = (lane >> 4) * 8;

    f32x4 acc[4][4];
#pragma unroll
    for (int i = 0; i < 4; ++i)
#pragma unroll
        for (int j = 0; j < 4; ++j) acc[i][j] = f32x4{0.f, 0.f, 0.f, 0.f};

    const int mt0 = (wave & 1) * 4;
    const int nt0 = (wave >> 1) * 4;

    for (int kb = 0; kb < K; kb += 32) {
        bf16x8 stg[8];
#pragma unroll
        for (int j = 0; j < 8; ++j) {
            int rr = rbase + j * 16;
            if (isA && rr >= M) rr = M - 1;           // clamp tail rows (stores guarded)
            stg[j] = *(const bf16x8*)(gsrc + (size_t)rr * K + kb + kq);
        }
#pragma unroll
        for (int j = 0; j < 8; ++j)
            *(bf16x8*)&S[wave][j][lane * 8] = stg[j];
        __syncthreads();

        bf16x8 ah[4], al[4], bh[4], bl[4];
#pragma unroll
        for (int i = 0; i < 4; ++i) {
            ah[i] = *(const bf16x8*)&S[0][mt0 + i][lane * 8];
            al[i] = *(const bf16x8*)&S[1][mt0 + i][lane * 8];
            bh[i] = *(const bf16x8*)&S[2][nt0 + i][lane * 8];
            bl[i] = *(const bf16x8*)&S[3][nt0 + i][lane * 8];
        }
#pragma unroll
        for (int i = 0; i < 4; ++i)
#pragma unroll
            for (int j = 0; j < 4; ++j) {
                acc[i][j] = __builtin_amdgcn_mfma_f32_16x16x32_bf16(ah[i], bh[j], acc[i][j], 0, 0, 0);
                acc[i][j] = __builtin_amdgcn_mfma_f32_16x16x32_bf16(ah[i], bl[j], acc[i][j], 0, 0, 0);
                acc[i][j] = __builtin_amdgcn_mfma_f32_16x16x32_bf16(al[i], bh[j], acc[i][j], 0, 0, 0);
            }
        __syncthreads();
    }

    // epilogue
    const int crow = (lane >> 4) * 4;
    const int ccol = lane & 15;
#pragma unroll
    for (int j = 0; j < 4; ++j) {
        int col = col0 + (nt0 + j) * 16 + ccol;
        float bv = RELU ? bias[col] : 0.f;
#pragma unroll
        for (int i = 0; i < 4; ++i) {
#pragma unroll
            for (int r = 0; r < 4; ++r) {
                int row = row0 + (mt0 + i) * 16 + crow + r;
                if (row < M) {
                    float v = acc[i][j][r];
                    if (RELU) v = fmaxf(v + bv, 0.f);
                    if (OBF16) {
                        short h = f2bf(v);
                        Ch[(size_t)row * N + col] = h;
                        Cl[(size_t)row * N + col] = f2bf(v - bf2f(h));
                    } else {
                        C[(size_t)row * N + col] = v;
                        if (SCB16)
                            Cb[(size_t)row * N + col] = (ushort)f2bf(v * dinv[row]);
                    }
                }
            }
        }
    }
}

// ---------------- bf16 gather aggregation (one wave per dst node, D=128) ----------------
// out[d] = [relu]( dd * Σ_{s in row d} hb[s]  +  dd²*hf[d] [+ bias] )
// hb rows are bf16, pre-scaled by dinv[src]. Indices wave-broadcast via __shfl
// so the inner loop's only memory op is the independent row gather.

template <bool BR, bool OBF16>
__launch_bounds__(256)
__global__ void agg_gather_kernel(const ushort* __restrict__ hb, const float* __restrict__ hf,
                                  const float* __restrict__ dinv,
                                  const int* __restrict__ rowptr, const int* __restrict__ csr,
                                  const float* __restrict__ bias, float* __restrict__ out,
                                  short* __restrict__ oh, short* __restrict__ ol, int N) {
    int wid = (blockIdx.x * blockDim.x + threadIdx.x) >> 6;  // node id
    int lane = threadIdx.x & 63;
    if (wid >= N) return;
    int lo = rowptr[wid], hi = rowptr[wid + 1];
    float dd = dinv[wid];

    float2 self = ((const float2*)hf)[(size_t)wid * 64 + lane];
    float accx = 0.f, accy = 0.f;

    for (int base = lo; base < hi; base += 64) {
        int cnt = min(64, hi - base);
        int sidx = csr[base + (lane < cnt ? lane : cnt - 1)];   // coalesced chunk load
        for (int j = 0; j < cnt; ++j) {
            int s = __shfl(sidx, j, 64);
            unsigned pv = *(const unsigned*)(hb + ((size_t)s << 7) + (lane << 1));
            accx += bf2f((short)(pv & 0xffff));
            accy += bf2f((short)(pv >> 16));
        }
    }

    float sc = dd * dd;
    float rx = fmaf(dd, accx, sc * self.x);
    float ry = fmaf(dd, accy, sc * self.y);
    if (BR) {
        float2 b = ((const float2*)bias)[lane];
        rx = fmaxf(rx + b.x, 0.f);
        ry = fmaxf(ry + b.y, 0.f);
    }
    if (OBF16) {
        short hx = f2bf(rx), hy = f2bf(ry);
        short2 hv; hv.x = hx; hv.y = hy;
        short2 lv; lv.x = f2bf(rx - bf2f(hx)); lv.y = f2bf(ry - bf2f(hy));
        *(short2*)&oh[(size_t)wid * 128 + lane * 2] = hv;
        *(short2*)&ol[(size_t)wid * 128 + lane * 2] = lv;
    } else {
        float2 o; o.x = rx; o.y = ry;
        ((float2*)out)[(size_t)wid * 64 + lane] = o;
    }
}

// ---------------- pool + fc ----------------

__launch_bounds__(128)
__global__ void pool_kernel(const float* __restrict__ h, const int* __restrict__ batch,
                            float* __restrict__ pool, int N) {
    int c = threadIdx.x;              // dim 0..127
    int i0 = blockIdx.x * PCH;
    if (i0 >= N) return;
    int i1 = min(i0 + PCH, N);
    int g = batch[i0];
    float acc = 0.f;
#pragma unroll 4
    for (int i = i0; i < i1; ++i) {
        int gi = batch[i];
        if (gi != g) {                // wave-uniform branch
            atomicAdd(&pool[g * HID2 + c], acc);
            acc = 0.f; g = gi;
        }
        acc += h[(size_t)i * HID2 + c];
    }
    atomicAdd(&pool[g * HID2 + c], acc);
}

__device__ __forceinline__ int lower_bound_i(const int* __restrict__ a, int n, int key) {
    int lo = 0, hi = n;
    while (lo < hi) {
        int mid = (lo + hi) >> 1;
        if (a[mid] < key) lo = mid + 1; else hi = mid;
    }
    return lo;
}

__global__ void fc_kernel(const float* __restrict__ pool, const int* __restrict__ batch,
                          const float* __restrict__ Wfc, const float* __restrict__ bfc,
                          float* __restrict__ out, int N) {
    int t = threadIdx.x;  // 256 = 64 graphs * 4 outputs
    int g = t >> 2, o = t & 3;
    int lo = lower_bound_i(batch, N, g);
    int hi = lower_bound_i(batch, N, g + 1);
    float acc = 0.f;
#pragma unroll 8
    for (int c = 0; c < HID2; ++c)
        acc = fmaf(pool[g * HID2 + c], Wfc[c * OUT_DIM + o], acc);
    float inv = 1.0f / fmaxf((float)(hi - lo), 1.0f);
    out[g * OUT_DIM + o] = acc * inv + bfc[o];
}

extern "C" void kernel_launch(void* const* d_in, const int* in_sizes, int n_in,
                              void* d_out, int out_size, void* d_ws, size_t ws_size,
                              hipStream_t stream) {
    const float* x   = (const float*)d_in[0];
    const int* src   = (const int*)d_in[1];
    const int* dst   = (const int*)d_in[2];
    const int* batch = (const int*)d_in[3];
    const float* W1  = (const float*)d_in[4];
    const float* b1  = (const float*)d_in[5];
    const float* W2  = (const float*)d_in[6];
    const float* b2  = (const float*)d_in[7];
    const float* Wfc = (const float*)d_in[8];
    const float* bfc = (const float*)d_in[9];
    float* out = (float*)d_out;

    const int N = in_sizes[0] / IN_DIM;  // 50000
    const int E = in_sizes[1];           // 640000
    const int NB = (N + 255) / 256;      // scan blocks (196)

    // ---- workspace layout (~94 MB; region aliasing) ----
    char* ws = (char*)d_ws;
    size_t off = 0;
    auto alloc = [&](size_t bytes) {
        char* p = ws + off;
        off = (off + bytes + 255) & ~(size_t)255;
        return p;
    };
    float* dinv   = (float*)alloc((size_t)N * 4);
    int*   count  = (int*)  alloc((size_t)N * 4);
    int*   cursor = (int*)  alloc((size_t)N * 4);
    int*   rowptr = (int*)  alloc((size_t)(N + 1) * 4);
    int*   bsums  = (int*)  alloc(256 * 4);
    int*   csr    = (int*)  alloc((size_t)E * 4);
    short* W1th   = (short*)alloc((size_t)IN_DIM * HID * 2);
    short* W1tl   = (short*)alloc((size_t)IN_DIM * HID * 2);
    short* W2th   = (short*)alloc((size_t)HID * HID2 * 2);
    short* W2tl   = (short*)alloc((size_t)HID * HID2 * 2);
    // region Z (12.8 MB): xb -> later h2b (bf16)
    ushort* xb    = (ushort*)alloc((size_t)N * IN_DIM * 2);
    // region X (25.6 MB): axh/axl -> later h2 (f32)
    short* axh    = (short*)alloc((size_t)N * IN_DIM * 2);
    short* axl    = (short*)alloc((size_t)N * IN_DIM * 2);
    // region Y (51.2 MB): a1h/a1l -> later a2 (f32, first half)
    short* a1h    = (short*)alloc((size_t)N * HID * 2);
    short* a1l    = (short*)alloc((size_t)N * HID * 2);
    float* pool   = (float*)alloc((size_t)NGRAPH * HID2 * 4);
    float*  h2  = (float*)axh;    // ax dead after gemm1
    ushort* h2b = xb;             // xb dead after agg1
    float*  a2  = (float*)a1h;    // a1 dead after gemm2

    // ---- CSR build (once; serves both layers) ----
    hipMemsetAsync(count, 0, (size_t)N * 4, stream);
    hist_kernel<<<(E + 255) / 256, 256, 0, stream>>>(dst, count, E);
    scan1_kernel<<<NB, 256, 0, stream>>>(count, bsums, N);
    scan2_kernel<<<1, 256, 0, stream>>>(bsums, NB);
    scan3_kernel<<<NB, 256, 0, stream>>>(count, bsums, rowptr, cursor, dinv, N, E);
    scatter_kernel<<<(E + 255) / 256, 256, 0, stream>>>(src, dst, cursor, csr, E);

    // ---- weight prep ----
    wprep_kernel<<<(IN_DIM * HID + 255) / 256, 256, 0, stream>>>(W1, W1th, W1tl, IN_DIM, HID);
    wprep_kernel<<<(HID * HID2 + 255) / 256, 256, 0, stream>>>(W2, W2th, W2tl, HID, HID2);

    // ---- layer 1: pre-scale+cast, aggregate (bf16 gathers), GEMM w/ bias+relu+split ----
    scale_cast_kernel<<<(N * 64 + 255) / 256, 256, 0, stream>>>(x, dinv, xb, N * 64);
    agg_gather_kernel<false, true><<<(N + 3) / 4, 256, 0, stream>>>(
        xb, x, dinv, rowptr, csr, nullptr, nullptr, axh, axl, N);
    gemm_tile_kernel<IN_DIM, HID, true, true, false><<<dim3(HID / 128, (N + 127) / 128), 256, 0, stream>>>(
        axh, axl, W1th, W1tl, b1, nullptr, a1h, a1l, nullptr, nullptr, N);

    // ---- layer 2: GEMM (f32 + scaled-bf16 out), aggregate w/ bias+relu ----
    gemm_tile_kernel<HID, HID2, false, false, true><<<dim3(HID2 / 128, (N + 127) / 128), 256, 0, stream>>>(
        a1h, a1l, W2th, W2tl, nullptr, h2, nullptr, nullptr, dinv, h2b, N);
    agg_gather_kernel<true, false><<<(N + 3) / 4, 256, 0, stream>>>(
        h2b, h2, dinv, rowptr, csr, b2, a2, nullptr, nullptr, N);

    // ---- pool + fc ----
    hipMemsetAsync(pool, 0, (size_t)NGRAPH * HID2 * 4, stream);
    pool_kernel<<<(N + PCH - 1) / PCH, HID2, 0, stream>>>(a2, batch, pool, N);
    fc_kernel<<<1, NGRAPH * OUT_DIM, 0, stream>>>(pool, batch, Wfc, bfc, out, N);
}